// Round 22
// baseline (168.998 us; speedup 1.0000x reference)
//
#include <hip/hip_runtime.h>
#include <hip/hip_bf16.h>
#include <hip/hip_fp16.h>

#define B_ 16
#define S_ 2048
#define D_ 128
#define QB 64
#define KT 64            // k-rows per tile
#define NT_ 32           // S/KT tiles
#define LOG2E 1.4426950408889634f

typedef __attribute__((ext_vector_type(8))) short short8;   // 8 x bf16 MFMA frag
typedef __attribute__((ext_vector_type(4))) float f32x4;    // MFMA accumulator
typedef __attribute__((ext_vector_type(4))) float f32x4v;
typedef __attribute__((ext_vector_type(4))) int i32x4;
typedef __attribute__((ext_vector_type(4))) unsigned short u16x4;

__device__ __forceinline__ float exp2fast(float x) {
  return __builtin_amdgcn_exp2f(x);    // v_exp_f32: native 2^x
}
__device__ __forceinline__ unsigned short f2bf(float f) {
  unsigned int u = __builtin_bit_cast(unsigned int, f);
  unsigned int r = (u + 0x7fffu + ((u >> 16) & 1u)) >> 16;   // RNE
  return (unsigned short)r;
}
__device__ __forceinline__ float bf2f(unsigned short h) {
  return __builtin_bit_cast(float, (unsigned int)h << 16);
}
// async global->LDS DMA, 16B per lane; LDS dest = wave-uniform base + lane*16
__device__ __forceinline__ void gl16(const void* g, void* l) {
  __builtin_amdgcn_global_load_lds(
      (const __attribute__((address_space(1))) unsigned int*)g,
      (__attribute__((address_space(3))) unsigned int*)l, 16, 0, 0);
}
// XCD-aware bijective swizzle (nwg % 8 == 0)
__device__ __forceinline__ int swz_bid(int bid, int nwg) {
  int cpx = nwg >> 3;
  return (bid & 7) * cpx + (bid >> 3);
}

// ---------- prep: fp32 -> bf16, y = x * sc * postmul ----------
__global__ void cvt_bf16_kernel(const float* __restrict__ x,
                                unsigned short* __restrict__ y,
                                const float* __restrict__ sc, float postmul,
                                int n4) {
  int i = blockIdx.x * blockDim.x + threadIdx.x;
  if (i >= n4) return;
  float s = (sc ? sc[0] : 1.0f) * postmul;
  float4 f = reinterpret_cast<const float4*>(x)[i];
  u16x4 o;
  o[0] = f2bf(f.x * s); o[1] = f2bf(f.y * s);
  o[2] = f2bf(f.z * s); o[3] = f2bf(f.w * s);
  reinterpret_cast<u16x4*>(y)[i] = o;
}

// ---------- prep: V [b][k][d] fp32 -> V^T [b][d][k] bf16 ----------
__global__ void vtrans_kernel(const float* __restrict__ v,
                              unsigned short* __restrict__ vT) {
  __shared__ float tile[32][33];
  int b = blockIdx.z, kt = blockIdx.x, dt = blockIdx.y;
  int t = threadIdx.x;
  int c = t & 31, r0 = t >> 5;
  const float* src = v + ((size_t)b * S_ + (size_t)kt * 32) * D_ + dt * 32;
#pragma unroll
  for (int i = 0; i < 4; i++) {
    int r = r0 + 8 * i;
    tile[r][c] = src[(size_t)r * D_ + c];
  }
  __syncthreads();
  unsigned short* dst = vT + ((size_t)b * D_ + dt * 32) * S_ + (size_t)kt * 32;
#pragma unroll
  for (int i = 0; i < 4; i++) {
    int r = r0 + 8 * i;
    dst[(size_t)r * S_ + c] = f2bf(tile[c][r]);
  }
}

// ---------- main: sweep-1 counted-vmcnt 3-deep pipeline; sweep-2 = R18 ----------
// LDS (aliased char pool, 72 KB + scratch):
//   sweep1: kbuf3[i] = pool + i*16384 (i=0..2)
//   sweep2: kbuf[c] = pool + c*16384; vbuf[c] = pool + 32768 + c*16384;
//           etile = pool + 65536
// Wave (QK^T): qh = w&1 (32 q-cols, 2 B-frags), kq = w>>1 (16 k-rows of 64).
// Wave (PV):   qh = w&1 (32 q-rows),             kq = w>>1 (32 d-cols).
// Q pre-scaled by scale*log2e: p = 2^s / sum 2^s (native v_exp).
__global__ __launch_bounds__(512, 4)
void attn_main_kernel(const unsigned short* __restrict__ qbf,   // scale*log2e folded
                      const unsigned short* __restrict__ kbf,
                      const unsigned short* __restrict__ vTb,
                      const void* __restrict__ maskp,
                      float* __restrict__ ctx,
                      float* __restrict__ att) {
  __shared__ __align__(16) char pool[73728];           // 72 KB
  __shared__ float zpart[8][2][16];
  __shared__ float iz_l[QB];

  const int tid = threadIdx.x;
  const int bid = swz_bid(blockIdx.x, B_ * (S_ / QB));
  const int b  = bid >> 5;            // 32 blocks per batch
  const int q0 = (bid & 31) << 6;

  const int w   = tid >> 6;
  const int l   = tid & 63;
  const int l16 = l & 15;
  const int lq  = l >> 4;
  const int qh  = w & 1;       // q-half (32 rows)
  const int kq  = w >> 1;      // QK^T: 16 k-rows of tile; PV: 32 d-cols

  const char* kbb = reinterpret_cast<const char*>(kbf + (((size_t)b * S_) << 7));
  const char* vbb = reinterpret_cast<const char*>(vTb + ((size_t)b * D_) * S_);

  // --- gload_lds geometry (R18-proven) ---
  const int krow_g = w * 4 + (l >> 4);
  const size_t ksrc = (size_t)krow_g * 256 + (((l & 15) * 16) ^ ((krow_g & 15) << 4));
  const int vrow_g = w * 8 + (l >> 3);
  const size_t vsrc = (size_t)vrow_g * (S_ * 2) + (((l & 7) * 16) ^ ((vrow_g & 7) << 4));
  const int ldsoff = w * 1024;   // wave-uniform dest base offset

  // --- issue K0, K1 (3-deep pipeline prologue) ---
  gl16(kbb + ksrc,                   pool + 0 * 16384 + ldsoff);
  gl16(kbb + ksrc + 8192,            pool + 0 * 16384 + ldsoff + 8192);
  gl16(kbb + KT * 256 + ksrc,        pool + 1 * 16384 + ldsoff);
  gl16(kbb + KT * 256 + ksrc + 8192, pool + 1 * 16384 + ldsoff + 8192);

  // --- mask layout detection (this syncthreads drains K0/K1 for all waves) ---
  int myv = 0;
  if (tid < 256) myv = (reinterpret_cast<const unsigned int*>(maskp)[tid] > 1u) ? 1 : 0;
  const int mask_is_byte = __syncthreads_or(myv);

  // --- Q B-frags: 2 groups x 4 ks, straight from global (L2) ---
  short8 qf[2][4];
#pragma unroll
  for (int qg = 0; qg < 2; ++qg) {
    const unsigned short* qp =
        qbf + (((size_t)(b * S_ + q0 + qh * 32 + qg * 16 + l16)) << 7) + lq * 8;
#pragma unroll
    for (int ks = 0; ks < 4; ks++)
      qf[qg][ks] = *reinterpret_cast<const short8*>(qp + ks * 32);
  }

  const unsigned char* mask8 = reinterpret_cast<const unsigned char*>(maskp);
  const int* mask32 = reinterpret_cast<const int*>(maskp);
  size_t mrowq[2];
#pragma unroll
  for (int qg = 0; qg < 2; ++qg)
    mrowq[qg] = ((size_t)b * S_ + q0 + qh * 32 + qg * 16 + l16) * S_ + kq * 16 + lq * 4;

  // --- mask pre-pass: all nibbles -> mbits (barrier-free; drains its own loads)
  unsigned int mbits[8] = {0, 0, 0, 0, 0, 0, 0, 0};
  if (mask_is_byte) {
#pragma unroll
    for (int t = 0; t < NT_; ++t) {
      unsigned int m0 = *reinterpret_cast<const unsigned int*>(mask8 + mrowq[0] + t * KT);
      unsigned int m1 = *reinterpret_cast<const unsigned int*>(mask8 + mrowq[1] + t * KT);
      unsigned int n0 = ((m0 & 0x000000ffu) ? 1u : 0u) | ((m0 & 0x0000ff00u) ? 2u : 0u) |
                        ((m0 & 0x00ff0000u) ? 4u : 0u) | ((m0 & 0xff000000u) ? 8u : 0u);
      unsigned int n1 = ((m1 & 0x000000ffu) ? 1u : 0u) | ((m1 & 0x0000ff00u) ? 2u : 0u) |
                        ((m1 & 0x00ff0000u) ? 4u : 0u) | ((m1 & 0xff000000u) ? 8u : 0u);
      mbits[t >> 2] |= (n0 | (n1 << 4)) << ((t & 3) * 8);
    }
  } else {
#pragma unroll
    for (int t = 0; t < NT_; ++t) {
      i32x4 m0 = *reinterpret_cast<const i32x4*>(mask32 + mrowq[0] + t * KT);
      i32x4 m1 = *reinterpret_cast<const i32x4*>(mask32 + mrowq[1] + t * KT);
      unsigned int n0 = (m0[0] ? 1u : 0u) | (m0[1] ? 2u : 0u) |
                        (m0[2] ? 4u : 0u) | (m0[3] ? 8u : 0u);
      unsigned int n1 = (m1[0] ? 1u : 0u) | (m1[1] ? 2u : 0u) |
                        (m1[2] ? 4u : 0u) | (m1[3] ? 8u : 0u);
      mbits[t >> 2] |= (n0 | (n1 << 4)) << ((t & 3) * 8);
    }
  }

  // ================= sweep 1: counted-vmcnt 3-deep pipeline =================
  // Per-iter vmem = exactly the 2 K-gloads (mask done; Q done). At the wait,
  // outstanding = K(t+1)[2, older] + K(t+2)[2, newer] -> vmcnt(2) guarantees
  // K(t+1) landed (in-order retirement); K(t+2) stays in flight across barrier.
  float Zl[2] = {0.0f, 0.0f};
  const int krow_f = kq * 16 + l16;                 // A-frag source row in tile
  const int kfx = (krow_f & 15) << 4;

  char* kb0 = pool + 0 * 16384;   // current
  char* kb1 = pool + 1 * 16384;   // next (landed by wait)
  char* kb2 = pool + 2 * 16384;   // in flight
  for (int t = 0; t < NT_; ++t) {
    if (t + 2 < NT_) {
      const char* src = kbb + (size_t)(t + 2) * (KT * 256);
      gl16(src + ksrc,        kb2 + ldsoff);
      gl16(src + ksrc + 8192, kb2 + ldsoff + 8192);
    }
    const char* kp = kb0 + krow_f * 256;
    f32x4 a0 = {0.f, 0.f, 0.f, 0.f}, a1 = {0.f, 0.f, 0.f, 0.f};
    __builtin_amdgcn_s_setprio(1);
#pragma unroll
    for (int ks = 0; ks < 4; ++ks) {
      short8 kfr = *reinterpret_cast<const short8*>(kp + ((ks * 64 + lq * 16) ^ kfx));
      a0 = __builtin_amdgcn_mfma_f32_16x16x32_bf16(kfr, qf[0][ks], a0, 0, 0, 0);
      a1 = __builtin_amdgcn_mfma_f32_16x16x32_bf16(kfr, qf[1][ks], a1, 0, 0, 0);
    }
    __builtin_amdgcn_s_setprio(0);
    const unsigned int nibs = mbits[t >> 2] >> ((t & 3) * 8);
#pragma unroll
    for (int r = 0; r < 4; ++r) {
      if (!(nibs & (1u << r)))  Zl[0] += exp2fast(a0[r]);
      if (!(nibs & (16u << r))) Zl[1] += exp2fast(a1[r]);
    }
    if (t + 2 < NT_) {
      asm volatile("s_waitcnt vmcnt(2) lgkmcnt(0)" ::: "memory");
    } else {
      asm volatile("s_waitcnt vmcnt(0) lgkmcnt(0)" ::: "memory");
    }
    __builtin_amdgcn_s_barrier();
    __builtin_amdgcn_sched_barrier(0);
    char* tmp = kb0; kb0 = kb1; kb1 = kb2; kb2 = tmp;
  }

  // ================= boundary: issue sweep-2 K0/V0; Z reduce =================
  gl16(kbb + ksrc,          pool + ldsoff);
  gl16(kbb + ksrc + 8192,   pool + ldsoff + 8192);
  gl16(vbb + vsrc,          pool + 32768 + ldsoff);
  gl16(vbb + vsrc + 262144, pool + 32768 + ldsoff + 8192);
#pragma unroll
  for (int qg = 0; qg < 2; ++qg) {
    Zl[qg] += __shfl_xor(Zl[qg], 16, 64);
    Zl[qg] += __shfl_xor(Zl[qg], 32, 64);
  }
  if (lq == 0) { zpart[w][0][l16] = Zl[0]; zpart[w][1][l16] = Zl[1]; }
  __syncthreads();
  if (tid < QB) {
    const int qh_ = tid >> 5, qg_ = (tid >> 4) & 1, r_ = tid & 15;
    float Z = 0.0f;
#pragma unroll
    for (int kk = 0; kk < 4; ++kk) Z += zpart[kk * 2 + qh_][qg_][r_];
    iz_l[tid] = 1.0f / Z;
  }
  __syncthreads();

  const float izq0 = iz_l[qh * 32 + l16];        // lane's q-row (qg=0)
  const float izq1 = iz_l[qh * 32 + 16 + l16];   // lane's q-row (qg=1)

  // ================= sweep 2 (R18 structure): recompute -> p -> att + PV =====
  char* etile = pool + 65536;
  f32x4 apv[2][2] = {{{0.f,0.f,0.f,0.f},{0.f,0.f,0.f,0.f}},
                     {{0.f,0.f,0.f,0.f},{0.f,0.f,0.f,0.f}}};
  for (int t = 0; t < NT_; ++t) {
    const int cur = t & 1;
    char* kcur = pool + cur * 16384;
    char* knxt = pool + (cur ^ 1) * 16384;
    char* vcur = pool + 32768 + cur * 16384;
    char* vnxt = pool + 32768 + (cur ^ 1) * 16384;
    if (t < NT_ - 1) {   // K(t+1): knxt last read before barrier1(t-1)
      const char* src = kbb + (size_t)(t + 1) * (KT * 256);
      gl16(src + ksrc,        knxt + ldsoff);
      gl16(src + ksrc + 8192, knxt + ldsoff + 8192);
    }
    // QK^T recompute from kcur
    const char* kp = kcur + krow_f * 256;
    f32x4 a0 = {0.f, 0.f, 0.f, 0.f}, a1 = {0.f, 0.f, 0.f, 0.f};
    __builtin_amdgcn_s_setprio(1);
#pragma unroll
    for (int ks = 0; ks < 4; ++ks) {
      short8 kfr = *reinterpret_cast<const short8*>(kp + ((ks * 64 + lq * 16) ^ kfx));
      a0 = __builtin_amdgcn_mfma_f32_16x16x32_bf16(kfr, qf[0][ks], a0, 0, 0, 0);
      a1 = __builtin_amdgcn_mfma_f32_16x16x32_bf16(kfr, qf[1][ks], a1, 0, 0, 0);
    }
    __builtin_amdgcn_s_setprio(0);
    const unsigned int nibs = mbits[t >> 2] >> ((t & 3) * 8);
    u16x4 eb[2];
#pragma unroll
    for (int r = 0; r < 4; ++r) {
      eb[0][r] = f2bf((nibs & (1u << r)) ? 0.0f : exp2fast(a0[r]) * izq0);
      eb[1][r] = f2bf((nibs & (16u << r)) ? 0.0f : exp2fast(a1[r]) * izq1);
    }
    __syncthreads();   // barrier1: prev tile's etile/vbuf reads complete
    // write e-tile (rows q, XOR-swizzled)
#pragma unroll
    for (int qg = 0; qg < 2; ++qg) {
      const int re = qh * 32 + qg * 16 + l16;
      *reinterpret_cast<u16x4*>(
          etile + re * 128 + ((kq * 32 + lq * 8) ^ ((re & 7) << 4))) = eb[qg];
    }
    __syncthreads();   // barrier2: e-tile visible; K(t+1)/V(t+1) landed
    // att: coalesced 256B row segments, f32 NT stores (p pre-normalized)
#pragma unroll
    for (int h = 0; h < 2; ++h) {
      const int re = w * 8 + h * 4 + (l >> 4);
      u16x4 ev = *reinterpret_cast<const u16x4*>(
          etile + re * 128 + (((l & 15) * 8) ^ ((re & 7) << 4)));
      f32x4v pv;
#pragma unroll
      for (int j = 0; j < 4; ++j) pv[j] = bf2f(ev[j]);
      __builtin_nontemporal_store(pv, reinterpret_cast<f32x4v*>(
          att + ((size_t)(b * S_ + q0 + re)) * S_ + t * KT + (l & 15) * 4));
    }
    // PV: kk-outer, explicit operand reuse
#pragma unroll
    for (int kk = 0; kk < 2; ++kk) {
      short8 afr[2], bfr[2];
#pragma unroll
      for (int qg = 0; qg < 2; ++qg) {
        const int re = qh * 32 + qg * 16 + l16;
        afr[qg] = *reinterpret_cast<const short8*>(
            etile + re * 128 + ((kk * 64 + lq * 16) ^ ((re & 7) << 4)));
      }
#pragma unroll
      for (int dg = 0; dg < 2; ++dg) {
        const int vr = kq * 32 + dg * 16 + l16;
        bfr[dg] = *reinterpret_cast<const short8*>(
            vcur + vr * 128 + ((kk * 64 + lq * 16) ^ ((vr & 7) << 4)));
      }
      __builtin_amdgcn_s_setprio(1);
#pragma unroll
      for (int qg = 0; qg < 2; ++qg)
#pragma unroll
        for (int dg = 0; dg < 2; ++dg)
          apv[qg][dg] = __builtin_amdgcn_mfma_f32_16x16x32_bf16(
              afr[qg], bfr[dg], apv[qg][dg], 0, 0, 0);
      __builtin_amdgcn_s_setprio(0);
    }
    // V(t+1) AFTER PV(t): vnxt last read before barrier1(t) -> safe
    if (t < NT_ - 1) {
      const char* vs2 = vbb + (size_t)(t + 1) * 128;
      gl16(vs2 + vsrc,          vnxt + ldsoff);
      gl16(vs2 + vsrc + 262144, vnxt + ldsoff + 8192);
    }
  }

  // --- ctx epilogue (apv already normalized) ---
#pragma unroll
  for (int qg = 0; qg < 2; ++qg) {
#pragma unroll
    for (int dg = 0; dg < 2; ++dg) {
#pragma unroll
      for (int r = 0; r < 4; ++r) {
        __builtin_nontemporal_store(
            apv[qg][dg][r],
            ctx + ((size_t)(b * S_ + q0 + qh * 32 + qg * 16 + lq * 4 + r)) * D_ +
                kq * 32 + dg * 16 + l16);
      }
    }
  }
}

extern "C" void kernel_launch(void* const* d_in, const int* in_sizes, int n_in,
                              void* d_out, int out_size, void* d_ws, size_t ws_size,
                              hipStream_t stream) {
  (void)in_sizes; (void)n_in; (void)out_size; (void)ws_size;
  const float* q = (const float*)d_in[0];
  const float* k = (const float*)d_in[1];
  const float* v = (const float*)d_in[2];
  const float* scale = (const float*)d_in[3];
  const void* mask = d_in[4];

  const size_t qkv_elems = (size_t)B_ * S_ * D_;
  unsigned short* qbf = (unsigned short*)d_ws;             // 8 MB
  unsigned short* kbf = qbf + qkv_elems;                   // 8 MB
  unsigned short* vTb = kbf + qkv_elems;                   // 8 MB

  float* ctx = (float*)d_out;                              // [B,S,D]
  float* att = ctx + (size_t)B_ * S_ * D_;                 // [B,S,S]

  const int n4 = B_ * S_ * D_ / 4;
  cvt_bf16_kernel<<<dim3((n4 + 255) / 256), dim3(256), 0, stream>>>(
      q, qbf, scale, LOG2E, n4);
  cvt_bf16_kernel<<<dim3((n4 + 255) / 256), dim3(256), 0, stream>>>(
      k, kbf, nullptr, 1.0f, n4);
  vtrans_kernel<<<dim3(S_ / 32, D_ / 32, B_), dim3(256), 0, stream>>>(v, vTb);
  attn_main_kernel<<<dim3(B_ * (S_ / QB)), dim3(512), 0, stream>>>(
      qbf, kbf, vTb, mask, ctx, att);
}